// Round 1
// baseline (4102.899 us; speedup 1.0000x reference)
//
#include <hip/hip_runtime.h>
#include <hip/hip_bf16.h>
#include <math.h>

#define N_NODES 32768
#define N_EDGES 524288
#define BATCH 64
#define SEQT 512

__device__ __forceinline__ float wave_reduce_sum(float v){
  #pragma unroll
  for (int o = 32; o > 0; o >>= 1) v += __shfl_down(v, o, 64);
  return v;
}

// vdst1[k] = sum_j Wdst1[k,j]*adst1[j]  (256), vdst2 likewise (128) at offset 256
__global__ void k_vdst(const float* __restrict__ Wdst1, const float* __restrict__ adst1,
                       const float* __restrict__ Wdst2, const float* __restrict__ adst2,
                       float* __restrict__ vdst){
  int t = threadIdx.x;
  if (t < 256){
    float s = 0.f;
    for (int j = 0; j < 128; j++) s += Wdst1[t*128+j]*adst1[j];
    vdst[t] = s;
  }
  if (t < 128){
    float s = 0.f;
    for (int j = 0; j < 128; j++) s += Wdst2[t*128+j]*adst2[j];
    vdst[256+t] = s;
  }
}

// hs[N,128] = X[:, :Kd] @ W[Kd,128]; X row stride ldx
__global__ void k_gemm128(const float* __restrict__ X, int ldx, int Kd,
                          const float* __restrict__ W, float* __restrict__ hs){
  __shared__ float Xs[16*256];
  int n0 = blockIdx.x * 16;
  int tid = threadIdx.x;
  for (int r = 0; r < 16; r++)
    for (int k = tid; k < Kd; k += 256)
      Xs[r*Kd + k] = X[(long)(n0+r)*ldx + k];
  __syncthreads();
  int c = tid & 127, rg = tid >> 7;
  float acc[8] = {0,0,0,0,0,0,0,0};
  for (int k = 0; k < Kd; k++){
    float wv = W[k*128 + c];
    #pragma unroll
    for (int r = 0; r < 8; r++) acc[r] += Xs[(rg*8+r)*Kd + k] * wv;
  }
  #pragma unroll
  for (int r = 0; r < 8; r++) hs[(long)(n0 + rg*8 + r)*128 + c] = acc[r];
}

// sv[n] = hs[n,:]@asrc ; dv[n] = X[n,:Kd]@vd   (one wave per node)
__global__ void k_sd(const float* __restrict__ hs, const float* __restrict__ asrc,
                     const float* __restrict__ X, int ldx, int Kd, const float* __restrict__ vd,
                     float* __restrict__ sv, float* __restrict__ dv){
  int n = blockIdx.x*4 + (threadIdx.x >> 6);
  int l = threadIdx.x & 63;
  float p = hs[(long)n*128 + l]*asrc[l] + hs[(long)n*128 + 64 + l]*asrc[64+l];
  float q = X[(long)n*ldx + l]*vd[l] + X[(long)n*ldx + 64 + l]*vd[64+l];
  if (Kd == 256)
    q += X[(long)n*ldx + 128 + l]*vd[128+l] + X[(long)n*ldx + 192 + l]*vd[192+l];
  p = wave_reduce_sum(p);
  q = wave_reduce_sum(q);
  if (l == 0){ sv[n] = p; dv[n] = q; }
}

__global__ void k_hist(const int* __restrict__ dst, int* __restrict__ cnt){
  int e = blockIdx.x*256 + threadIdx.x;
  if (e < N_EDGES) atomicAdd(&cnt[dst[e]], 1);
}

// exclusive scan of cnt (N=32768 = 1024 threads * 32), writes off[0..N], zeroes cnt
__global__ void k_scan(int* __restrict__ cnt, int* __restrict__ off){
  __shared__ int part[1024];
  int t = threadIdx.x;
  int base_i = t*32;
  int s = 0;
  #pragma unroll
  for (int i = 0; i < 32; i++) s += cnt[base_i + i];
  part[t] = s;
  __syncthreads();
  for (int o = 1; o < 1024; o <<= 1){
    int v = (t >= o) ? part[t-o] : 0;
    __syncthreads();
    part[t] += v;
    __syncthreads();
  }
  int run = part[t] - s; // exclusive prefix of this thread's segment
  for (int i = 0; i < 32; i++){
    off[base_i + i] = run;
    run += cnt[base_i + i];
    cnt[base_i + i] = 0;
  }
  if (t == 1023) off[N_NODES] = part[1023];
}

__global__ void k_scatter(const int* __restrict__ dst, const int* __restrict__ off,
                          int* __restrict__ cnt, int* __restrict__ eid){
  int e = blockIdx.x*256 + threadIdx.x;
  if (e < N_EDGES){
    int d0 = dst[e];
    int pos = off[d0] + atomicAdd(&cnt[d0], 1);
    eid[pos] = e;
  }
}

// one wave per dst node: online softmax over in-edges, weighted sum of hs[src]
__global__ void k_agg(const int* __restrict__ eid, const int* __restrict__ off,
                      const int* __restrict__ src,
                      const float* __restrict__ sv, const float* __restrict__ dv,
                      const float* __restrict__ hs, const float* __restrict__ bias,
                      float* __restrict__ emb, int colOff, int doRelu){
  int n = blockIdx.x*4 + (threadIdx.x >> 6);
  int l = threadIdx.x & 63;
  int eb = off[n], ee = off[n+1];
  float dn = dv[n];
  float m = -1e30f, den = 0.f, a0 = 0.f, a1 = 0.f;
  for (int i = eb; i < ee; i++){
    int e = eid[i];
    int sn = src[e];
    float al = sv[sn] + dn;
    al = al > 0.f ? al : 0.2f*al;       // leaky_relu 0.2
    float nm = fmaxf(m, al);
    float scl = __expf(m - nm);
    float p   = __expf(al - nm);
    den = den*scl + p;
    a0  = a0*scl + p*hs[(long)sn*128 + l];
    a1  = a1*scl + p*hs[(long)sn*128 + 64 + l];
    m = nm;
  }
  float inv = 1.f/(den + 1e-16f);
  float v0 = a0*inv + bias[l];
  float v1 = a1*inv + bias[64+l];
  if (doRelu){ v0 = fmaxf(v0, 0.f); v1 = fmaxf(v1, 0.f); }
  emb[(long)n*256 + colOff + l] = v0;
  emb[(long)n*256 + colOff + 64 + l] = v1;
}

// xg[N,768] = emb[N,256] @ Wi[256,768] + bi
__global__ void k_xg(const float* __restrict__ emb, const float* __restrict__ Wi,
                     const float* __restrict__ bi, float* __restrict__ xg){
  __shared__ float Xs[16*256];
  int n0 = blockIdx.x*16;
  int tid = threadIdx.x;
  for (int r = 0; r < 16; r++)
    for (int k = tid; k < 256; k += 256)
      Xs[r*256 + k] = emb[(long)(n0+r)*256 + k];
  __syncthreads();
  float acc[16][3];
  #pragma unroll
  for (int r = 0; r < 16; r++){ acc[r][0]=0.f; acc[r][1]=0.f; acc[r][2]=0.f; }
  for (int k = 0; k < 256; k++){
    float w0 = Wi[k*768 + tid];
    float w1 = Wi[k*768 + 256 + tid];
    float w2 = Wi[k*768 + 512 + tid];
    #pragma unroll
    for (int r = 0; r < 16; r++){
      float xv = Xs[r*256 + k];
      acc[r][0] += xv*w0; acc[r][1] += xv*w1; acc[r][2] += xv*w2;
    }
  }
  float bv0 = bi[tid], bv1 = bi[256+tid], bv2 = bi[512+tid];
  #pragma unroll
  for (int r = 0; r < 16; r++){
    long rowp = (long)(n0+r)*768;
    xg[rowp + tid]       = acc[r][0] + bv0;
    xg[rowp + 256 + tid] = acc[r][1] + bv1;
    xg[rowp + 512 + tid] = acc[r][2] + bv2;
  }
}

// sequential GRU: one block per batch, 768 threads (one per gate column)
__global__ void __launch_bounds__(768) k_gru(const float* __restrict__ xg,
                     const float* __restrict__ Wh, const float* __restrict__ bh,
                     float* __restrict__ hseq){
  __shared__ float h_lds[256];
  __shared__ float gh[768];
  int b = blockIdx.x;
  int j = threadIdx.x;
  if (j < 256) h_lds[j] = 0.f;
  __syncthreads();
  float bhv = bh[j];
  for (int t = 0; t < SEQT; t++){
    float acc = bhv;
    for (int k = 0; k < 256; k++) acc += h_lds[k]*Wh[k*768 + j];
    gh[j] = acc;
    __syncthreads();
    if (j < 256){
      long rowp = ((long)b*SEQT + t)*768;
      float xr = xg[rowp + j], xz = xg[rowp + 256 + j], xn = xg[rowp + 512 + j];
      float r = 1.f/(1.f + __expf(-(xr + gh[j])));
      float z = 1.f/(1.f + __expf(-(xz + gh[256+j])));
      float nn = tanhf(xn + r*gh[512+j]);
      float hv = (1.f - z)*nn + z*h_lds[j];
      h_lds[j] = hv;
      hseq[((long)b*SEQT + t)*256 + j] = hv;
    }
    __syncthreads();
  }
}

__global__ void k_scores(const float* __restrict__ hseq, const float* __restrict__ w_att,
                         const float* __restrict__ b_att, float* __restrict__ scores){
  int n = blockIdx.x*4 + (threadIdx.x >> 6);
  int l = threadIdx.x & 63;
  const float* hp = hseq + (long)n*256;
  float p = hp[l]*w_att[l] + hp[64+l]*w_att[64+l]
          + hp[128+l]*w_att[128+l] + hp[192+l]*w_att[192+l];
  p = wave_reduce_sum(p);
  if (l == 0) scores[n] = p + b_att[0];
}

// per-batch masked softmax over time + context + MLP head
__global__ void k_final(const float* __restrict__ scores, const int* __restrict__ lengths,
                        const float* __restrict__ hseq,
                        const float* __restrict__ fc1_w, const float* __restrict__ fc1_b,
                        const float* __restrict__ fc2_w, const float* __restrict__ fc2_b,
                        float* __restrict__ out){
  __shared__ float sc[512];
  __shared__ float red[256];
  __shared__ float ctxs[256];
  __shared__ float z1s[128];
  int b = blockIdx.x, t = threadIdx.x;
  int len = lengths[b];
  for (int i = t; i < 512; i += 256){
    float v = scores[b*512 + i];
    sc[i] = (i < len) ? v : -1e9f;
  }
  __syncthreads();
  red[t] = fmaxf(sc[t], sc[t+256]);
  __syncthreads();
  for (int o = 128; o > 0; o >>= 1){
    if (t < o) red[t] = fmaxf(red[t], red[t+o]);
    __syncthreads();
  }
  float m = red[0];
  __syncthreads();
  float e0 = __expf(sc[t] - m), e1 = __expf(sc[t+256] - m);
  red[t] = e0 + e1;
  __syncthreads();
  for (int o = 128; o > 0; o >>= 1){
    if (t < o) red[t] += red[t+o];
    __syncthreads();
  }
  float den = red[0];
  __syncthreads();
  sc[t] = e0/den; sc[t+256] = e1/den;
  __syncthreads();
  float acc = 0.f;
  for (int i = 0; i < 512; i++) acc += sc[i]*hseq[((long)b*512 + i)*256 + t];
  ctxs[t] = acc;
  __syncthreads();
  if (t < 128){
    float a = fc1_b[t];
    for (int k = 0; k < 256; k++) a += ctxs[k]*fc1_w[k*128 + t];
    z1s[t] = fmaxf(a, 0.f);
  }
  __syncthreads();
  if (t < 64){
    float p = z1s[t]*fc2_w[t] + z1s[t+64]*fc2_w[t+64];
    p = wave_reduce_sum(p);
    if (t == 0) out[b] = p + fc2_b[0];
  }
}

extern "C" void kernel_launch(void* const* d_in, const int* in_sizes, int n_in,
                              void* d_out, int out_size, void* d_ws, size_t ws_size,
                              hipStream_t stream) {
  const float* x     = (const float*)d_in[0];
  const int*   edge  = (const int*)d_in[1];
  const int*   lengths = (const int*)d_in[2];
  const float* Wsrc1 = (const float*)d_in[3];
  const float* Wdst1 = (const float*)d_in[4];
  const float* asrc1 = (const float*)d_in[5];
  const float* adst1 = (const float*)d_in[6];
  const float* b1    = (const float*)d_in[7];
  const float* Wsrc2 = (const float*)d_in[8];
  const float* Wdst2 = (const float*)d_in[9];
  const float* asrc2 = (const float*)d_in[10];
  const float* adst2 = (const float*)d_in[11];
  const float* b2    = (const float*)d_in[12];
  const float* Wi    = (const float*)d_in[13];
  const float* Wh    = (const float*)d_in[14];
  const float* bi    = (const float*)d_in[15];
  const float* bh    = (const float*)d_in[16];
  const float* w_att = (const float*)d_in[17];
  const float* b_att = (const float*)d_in[18];
  const float* fc1_w = (const float*)d_in[19];
  const float* fc1_b = (const float*)d_in[20];
  const float* fc2_w = (const float*)d_in[21];
  const float* fc2_b = (const float*)d_in[22];
  float* out = (float*)d_out;

  const int* srcp = edge;
  const int* dstp = edge + N_EDGES;

  float* ws   = (float*)d_ws;
  float* emb  = ws;                              // N*256
  float* xg   = emb  + (size_t)N_NODES*256;      // N*768
  float* hseq = xg   + (size_t)N_NODES*768;      // N*256
  float* hs   = hseq + (size_t)N_NODES*256;      // N*128
  float* sv   = hs   + (size_t)N_NODES*128;      // N
  float* dv   = sv   + N_NODES;                  // N
  float* vdst = dv   + N_NODES;                  // 384
  float* scores = vdst + 384;                    // N
  int* csr_cnt = (int*)(scores + N_NODES);       // N
  int* csr_off = csr_cnt + N_NODES;              // N+1
  int* csr_eid = csr_off + N_NODES + 1;          // E

  hipMemsetAsync(csr_cnt, 0, N_NODES*sizeof(int), stream);
  k_vdst<<<1, 256, 0, stream>>>(Wdst1, adst1, Wdst2, adst2, vdst);

  // GAT layer 1
  k_gemm128<<<N_NODES/16, 256, 0, stream>>>(x, 256, 256, Wsrc1, hs);
  k_sd<<<N_NODES/4, 256, 0, stream>>>(hs, asrc1, x, 256, 256, vdst, sv, dv);
  k_hist<<<N_EDGES/256, 256, 0, stream>>>(dstp, csr_cnt);
  k_scan<<<1, 1024, 0, stream>>>(csr_cnt, csr_off);
  k_scatter<<<N_EDGES/256, 256, 0, stream>>>(dstp, csr_off, csr_cnt, csr_eid);
  k_agg<<<N_NODES/4, 256, 0, stream>>>(csr_eid, csr_off, srcp, sv, dv, hs, b1, emb, 0, 1);

  // GAT layer 2 (input = h1 in emb cols 0..127)
  k_gemm128<<<N_NODES/16, 256, 0, stream>>>(emb, 256, 128, Wsrc2, hs);
  k_sd<<<N_NODES/4, 256, 0, stream>>>(hs, asrc2, emb, 256, 128, vdst+256, sv, dv);
  k_agg<<<N_NODES/4, 256, 0, stream>>>(csr_eid, csr_off, srcp, sv, dv, hs, b2, emb, 128, 0);

  // GRU input gates + scan
  k_xg<<<N_NODES/16, 256, 0, stream>>>(emb, Wi, bi, xg);
  k_gru<<<BATCH, 768, 0, stream>>>(xg, Wh, bh, hseq);

  // attention pooling + MLP head
  k_scores<<<N_NODES/4, 256, 0, stream>>>(hseq, w_att, b_att, scores);
  k_final<<<BATCH, 256, 0, stream>>>(scores, lengths, hseq, fc1_w, fc1_b, fc2_w, fc2_b, out);
}

// Round 2
// 1454.498 us; speedup vs baseline: 2.8208x; 2.8208x over previous
//
#include <hip/hip_runtime.h>
#include <hip/hip_bf16.h>
#include <math.h>

#define N_NODES 32768
#define N_EDGES 524288
#define BATCH 64
#define SEQT 512

__device__ __forceinline__ float wave_reduce_sum(float v){
  #pragma unroll
  for (int o = 32; o > 0; o >>= 1) v += __shfl_down(v, o, 64);
  return v;
}

// round-to-nearest-even fp32 -> bf16 (as high 16 bits), packed pair
__device__ __forceinline__ unsigned bf16_rne(float f){
  unsigned u = __float_as_uint(f);
  return (u + 0x7FFFu + ((u >> 16) & 1u)) >> 16;
}
__device__ __forceinline__ unsigned pack2_rne(float lo, float hi){
  return bf16_rne(lo) | (bf16_rne(hi) << 16);
}

__device__ __forceinline__ void dot2bf(float& acc, unsigned w, unsigned h){
  asm("v_dot2_f32_bf16 %0, %1, %2, %0" : "+v"(acc) : "v"(w), "v"(h));
}

// vdst1[k] = sum_j Wdst1[k,j]*adst1[j]  (256), vdst2 likewise (128) at offset 256
__global__ void k_vdst(const float* __restrict__ Wdst1, const float* __restrict__ adst1,
                       const float* __restrict__ Wdst2, const float* __restrict__ adst2,
                       float* __restrict__ vdst){
  int t = threadIdx.x;
  if (t < 256){
    float s = 0.f;
    for (int j = 0; j < 128; j++) s += Wdst1[t*128+j]*adst1[j];
    vdst[t] = s;
  }
  if (t < 128){
    float s = 0.f;
    for (int j = 0; j < 128; j++) s += Wdst2[t*128+j]*adst2[j];
    vdst[256+t] = s;
  }
}

// hs[N,128] = X[:, :Kd] @ W[Kd,128]; X row stride ldx
__global__ void k_gemm128(const float* __restrict__ X, int ldx, int Kd,
                          const float* __restrict__ W, float* __restrict__ hs){
  __shared__ float Xs[16*256];
  int n0 = blockIdx.x * 16;
  int tid = threadIdx.x;
  for (int r = 0; r < 16; r++)
    for (int k = tid; k < Kd; k += 256)
      Xs[r*Kd + k] = X[(long)(n0+r)*ldx + k];
  __syncthreads();
  int c = tid & 127, rg = tid >> 7;
  float acc[8] = {0,0,0,0,0,0,0,0};
  for (int k = 0; k < Kd; k++){
    float wv = W[k*128 + c];
    #pragma unroll
    for (int r = 0; r < 8; r++) acc[r] += Xs[(rg*8+r)*Kd + k] * wv;
  }
  #pragma unroll
  for (int r = 0; r < 8; r++) hs[(long)(n0 + rg*8 + r)*128 + c] = acc[r];
}

// sv[n] = hs[n,:]@asrc ; dv[n] = X[n,:Kd]@vd   (one wave per node)
__global__ void k_sd(const float* __restrict__ hs, const float* __restrict__ asrc,
                     const float* __restrict__ X, int ldx, int Kd, const float* __restrict__ vd,
                     float* __restrict__ sv, float* __restrict__ dv){
  int n = blockIdx.x*4 + (threadIdx.x >> 6);
  int l = threadIdx.x & 63;
  float p = hs[(long)n*128 + l]*asrc[l] + hs[(long)n*128 + 64 + l]*asrc[64+l];
  float q = X[(long)n*ldx + l]*vd[l] + X[(long)n*ldx + 64 + l]*vd[64+l];
  if (Kd == 256)
    q += X[(long)n*ldx + 128 + l]*vd[128+l] + X[(long)n*ldx + 192 + l]*vd[192+l];
  p = wave_reduce_sum(p);
  q = wave_reduce_sum(q);
  if (l == 0){ sv[n] = p; dv[n] = q; }
}

__global__ void k_hist(const int* __restrict__ dst, int* __restrict__ cnt){
  int e = blockIdx.x*256 + threadIdx.x;
  if (e < N_EDGES) atomicAdd(&cnt[dst[e]], 1);
}

// exclusive scan of cnt (N=32768 = 1024 threads * 32), writes off[0..N], zeroes cnt
__global__ void k_scan(int* __restrict__ cnt, int* __restrict__ off){
  __shared__ int part[1024];
  int t = threadIdx.x;
  int base_i = t*32;
  int s = 0;
  #pragma unroll
  for (int i = 0; i < 32; i++) s += cnt[base_i + i];
  part[t] = s;
  __syncthreads();
  for (int o = 1; o < 1024; o <<= 1){
    int v = (t >= o) ? part[t-o] : 0;
    __syncthreads();
    part[t] += v;
    __syncthreads();
  }
  int run = part[t] - s; // exclusive prefix of this thread's segment
  for (int i = 0; i < 32; i++){
    off[base_i + i] = run;
    run += cnt[base_i + i];
    cnt[base_i + i] = 0;
  }
  if (t == 1023) off[N_NODES] = part[1023];
}

__global__ void k_scatter(const int* __restrict__ dst, const int* __restrict__ off,
                          int* __restrict__ cnt, int* __restrict__ eid){
  int e = blockIdx.x*256 + threadIdx.x;
  if (e < N_EDGES){
    int d0 = dst[e];
    int pos = off[d0] + atomicAdd(&cnt[d0], 1);
    eid[pos] = e;
  }
}

// one wave per dst node: online softmax over in-edges, weighted sum of hs[src]
__global__ void k_agg(const int* __restrict__ eid, const int* __restrict__ off,
                      const int* __restrict__ src,
                      const float* __restrict__ sv, const float* __restrict__ dv,
                      const float* __restrict__ hs, const float* __restrict__ bias,
                      float* __restrict__ emb, int colOff, int doRelu){
  int n = blockIdx.x*4 + (threadIdx.x >> 6);
  int l = threadIdx.x & 63;
  int eb = off[n], ee = off[n+1];
  float dn = dv[n];
  float m = -1e30f, den = 0.f, a0 = 0.f, a1 = 0.f;
  for (int i = eb; i < ee; i++){
    int e = eid[i];
    int sn = src[e];
    float al = sv[sn] + dn;
    al = al > 0.f ? al : 0.2f*al;       // leaky_relu 0.2
    float nm = fmaxf(m, al);
    float scl = __expf(m - nm);
    float p   = __expf(al - nm);
    den = den*scl + p;
    a0  = a0*scl + p*hs[(long)sn*128 + l];
    a1  = a1*scl + p*hs[(long)sn*128 + 64 + l];
    m = nm;
  }
  float inv = 1.f/(den + 1e-16f);
  float v0 = a0*inv + bias[l];
  float v1 = a1*inv + bias[64+l];
  if (doRelu){ v0 = fmaxf(v0, 0.f); v1 = fmaxf(v1, 0.f); }
  emb[(long)n*256 + colOff + l] = v0;
  emb[(long)n*256 + colOff + 64 + l] = v1;
}

// xg[N,768] = emb[N,256] @ Wi[256,768] + bi
__global__ void k_xg(const float* __restrict__ emb, const float* __restrict__ Wi,
                     const float* __restrict__ bi, float* __restrict__ xg){
  __shared__ float Xs[16*256];
  int n0 = blockIdx.x*16;
  int tid = threadIdx.x;
  for (int r = 0; r < 16; r++)
    for (int k = tid; k < 256; k += 256)
      Xs[r*256 + k] = emb[(long)(n0+r)*256 + k];
  __syncthreads();
  float acc[16][3];
  #pragma unroll
  for (int r = 0; r < 16; r++){ acc[r][0]=0.f; acc[r][1]=0.f; acc[r][2]=0.f; }
  for (int k = 0; k < 256; k++){
    float w0 = Wi[k*768 + tid];
    float w1 = Wi[k*768 + 256 + tid];
    float w2 = Wi[k*768 + 512 + tid];
    #pragma unroll
    for (int r = 0; r < 16; r++){
      float xv = Xs[r*256 + k];
      acc[r][0] += xv*w0; acc[r][1] += xv*w1; acc[r][2] += xv*w2;
    }
  }
  float bv0 = bi[tid], bv1 = bi[256+tid], bv2 = bi[512+tid];
  #pragma unroll
  for (int r = 0; r < 16; r++){
    long rowp = (long)(n0+r)*768;
    xg[rowp + tid]       = acc[r][0] + bv0;
    xg[rowp + 256 + tid] = acc[r][1] + bv1;
    xg[rowp + 512 + tid] = acc[r][2] + bv2;
  }
}

// GRU with register+LDS-resident bf16 Wh.
// One block per batch, 768 threads (one per gate column j).
// Thread j holds Wh[k][j] for k in [0,192) as 96 packed bf16 pairs in VGPRs;
// k in [192,256) lives in LDS (32 pairs x 768 cols). h is broadcast from LDS
// as bf16 pairs; GRU state h stays fp32 in a per-thread register.
__global__ void __launch_bounds__(768, 3) k_gru2(
                     const float* __restrict__ xg,
                     const float* __restrict__ Wh, const float* __restrict__ bh,
                     float* __restrict__ hseq){
  extern __shared__ unsigned char smem[];
  unsigned* Wl = (unsigned*)smem;            // 32*768 u32 = 96 KB
  unsigned* hp = Wl + 32*768;                // 128 u32 (h as bf16 pairs)
  float* ghs   = (float*)(hp + 128);         // 768 f32
  float* xs    = ghs + 768;                  // 2*768 f32 (double-buffered xg row)

  int b = blockIdx.x;
  int j = threadIdx.x;

  // ---- load 96 packed weight pairs into registers (k = 0..191) ----
  unsigned w[96];
  #pragma unroll
  for (int m = 0; m < 96; m++)
    w[m] = pack2_rne(Wh[(2*m)*768 + j], Wh[(2*m+1)*768 + j]);

  // ---- LDS weights (k = 192..255 -> pairs 96..127) ----
  #pragma unroll
  for (int m = 0; m < 32; m++)
    Wl[m*768 + j] = pack2_rne(Wh[(192 + 2*m)*768 + j], Wh[(193 + 2*m)*768 + j]);

  if (j < 128) hp[j] = 0u;
  float bhv = bh[j];
  float hreg = 0.f;                       // fp32 GRU state (threads j<256)
  float xcur = xg[((long)b*SEQT)*768 + j];
  __syncthreads();

  for (int t = 0; t < SEQT; t++){
    xs[(t & 1)*768 + j] = xcur;

    float a0 = 0.f, a1 = 0.f, a2 = 0.f, a3 = 0.f;
    const uint4* hp4 = (const uint4*)hp;
    #pragma unroll
    for (int q = 0; q < 24; q++){
      uint4 h4 = hp4[q];                  // broadcast ds_read_b128
      dot2bf(a0, w[4*q+0], h4.x);
      dot2bf(a1, w[4*q+1], h4.y);
      dot2bf(a2, w[4*q+2], h4.z);
      dot2bf(a3, w[4*q+3], h4.w);
    }
    #pragma unroll
    for (int q = 24; q < 32; q++){
      uint4 h4 = hp4[q];
      int m4 = (q - 24)*4;
      dot2bf(a0, Wl[(m4+0)*768 + j], h4.x);
      dot2bf(a1, Wl[(m4+1)*768 + j], h4.y);
      dot2bf(a2, Wl[(m4+2)*768 + j], h4.z);
      dot2bf(a3, Wl[(m4+3)*768 + j], h4.w);
    }
    ghs[j] = ((a0 + a1) + (a2 + a3)) + bhv;

    int tn = (t + 1 < SEQT) ? t + 1 : SEQT - 1;
    float xnext = xg[((long)b*SEQT + tn)*768 + j];   // prefetch next row

    __syncthreads();

    if (j < 256){
      float xr = xs[(t & 1)*768 + j];
      float xz = xs[(t & 1)*768 + 256 + j];
      float xn = xs[(t & 1)*768 + 512 + j];
      float r = 1.f/(1.f + __expf(-(xr + ghs[j])));
      float z = 1.f/(1.f + __expf(-(xz + ghs[256 + j])));
      float nn = tanhf(xn + r*ghs[512 + j]);
      float hv = (1.f - z)*nn + z*hreg;
      hreg = hv;
      hseq[((long)b*SEQT + t)*256 + j] = hv;
      float partner = __shfl_xor(hv, 1, 64);
      if ((j & 1) == 0) hp[j >> 1] = pack2_rne(hv, partner);
    }
    xcur = xnext;
    __syncthreads();
  }
}

__global__ void k_scores(const float* __restrict__ hseq, const float* __restrict__ w_att,
                         const float* __restrict__ b_att, float* __restrict__ scores){
  int n = blockIdx.x*4 + (threadIdx.x >> 6);
  int l = threadIdx.x & 63;
  const float* hp = hseq + (long)n*256;
  float p = hp[l]*w_att[l] + hp[64+l]*w_att[64+l]
          + hp[128+l]*w_att[128+l] + hp[192+l]*w_att[192+l];
  p = wave_reduce_sum(p);
  if (l == 0) scores[n] = p + b_att[0];
}

// per-batch masked softmax over time + context + MLP head
__global__ void k_final(const float* __restrict__ scores, const int* __restrict__ lengths,
                        const float* __restrict__ hseq,
                        const float* __restrict__ fc1_w, const float* __restrict__ fc1_b,
                        const float* __restrict__ fc2_w, const float* __restrict__ fc2_b,
                        float* __restrict__ out){
  __shared__ float sc[512];
  __shared__ float red[256];
  __shared__ float ctxs[256];
  __shared__ float z1s[128];
  int b = blockIdx.x, t = threadIdx.x;
  int len = lengths[b];
  for (int i = t; i < 512; i += 256){
    float v = scores[b*512 + i];
    sc[i] = (i < len) ? v : -1e9f;
  }
  __syncthreads();
  red[t] = fmaxf(sc[t], sc[t+256]);
  __syncthreads();
  for (int o = 128; o > 0; o >>= 1){
    if (t < o) red[t] = fmaxf(red[t], red[t+o]);
    __syncthreads();
  }
  float m = red[0];
  __syncthreads();
  float e0 = __expf(sc[t] - m), e1 = __expf(sc[t+256] - m);
  red[t] = e0 + e1;
  __syncthreads();
  for (int o = 128; o > 0; o >>= 1){
    if (t < o) red[t] += red[t+o];
    __syncthreads();
  }
  float den = red[0];
  __syncthreads();
  sc[t] = e0/den; sc[t+256] = e1/den;
  __syncthreads();
  float acc = 0.f;
  for (int i = 0; i < 512; i++) acc += sc[i]*hseq[((long)b*512 + i)*256 + t];
  ctxs[t] = acc;
  __syncthreads();
  if (t < 128){
    float a = fc1_b[t];
    for (int k = 0; k < 256; k++) a += ctxs[k]*fc1_w[k*128 + t];
    z1s[t] = fmaxf(a, 0.f);
  }
  __syncthreads();
  if (t < 64){
    float p = z1s[t]*fc2_w[t] + z1s[t+64]*fc2_w[t+64];
    p = wave_reduce_sum(p);
    if (t == 0) out[b] = p + fc2_b[0];
  }
}

extern "C" void kernel_launch(void* const* d_in, const int* in_sizes, int n_in,
                              void* d_out, int out_size, void* d_ws, size_t ws_size,
                              hipStream_t stream) {
  const float* x     = (const float*)d_in[0];
  const int*   edge  = (const int*)d_in[1];
  const int*   lengths = (const int*)d_in[2];
  const float* Wsrc1 = (const float*)d_in[3];
  const float* Wdst1 = (const float*)d_in[4];
  const float* asrc1 = (const float*)d_in[5];
  const float* adst1 = (const float*)d_in[6];
  const float* b1    = (const float*)d_in[7];
  const float* Wsrc2 = (const float*)d_in[8];
  const float* Wdst2 = (const float*)d_in[9];
  const float* asrc2 = (const float*)d_in[10];
  const float* adst2 = (const float*)d_in[11];
  const float* b2    = (const float*)d_in[12];
  const float* Wi    = (const float*)d_in[13];
  const float* Wh    = (const float*)d_in[14];
  const float* bi    = (const float*)d_in[15];
  const float* bh    = (const float*)d_in[16];
  const float* w_att = (const float*)d_in[17];
  const float* b_att = (const float*)d_in[18];
  const float* fc1_w = (const float*)d_in[19];
  const float* fc1_b = (const float*)d_in[20];
  const float* fc2_w = (const float*)d_in[21];
  const float* fc2_b = (const float*)d_in[22];
  float* out = (float*)d_out;

  const int* srcp = edge;
  const int* dstp = edge + N_EDGES;

  float* ws   = (float*)d_ws;
  float* emb  = ws;                              // N*256
  float* xg   = emb  + (size_t)N_NODES*256;      // N*768
  float* hseq = xg   + (size_t)N_NODES*768;      // N*256
  float* hs   = hseq + (size_t)N_NODES*256;      // N*128
  float* sv   = hs   + (size_t)N_NODES*128;      // N
  float* dv   = sv   + N_NODES;                  // N
  float* vdst = dv   + N_NODES;                  // 384
  float* scores = vdst + 384;                    // N
  int* csr_cnt = (int*)(scores + N_NODES);       // N
  int* csr_off = csr_cnt + N_NODES;              // N+1
  int* csr_eid = csr_off + N_NODES + 1;          // E

  hipMemsetAsync(csr_cnt, 0, N_NODES*sizeof(int), stream);
  k_vdst<<<1, 256, 0, stream>>>(Wdst1, adst1, Wdst2, adst2, vdst);

  // GAT layer 1
  k_gemm128<<<N_NODES/16, 256, 0, stream>>>(x, 256, 256, Wsrc1, hs);
  k_sd<<<N_NODES/4, 256, 0, stream>>>(hs, asrc1, x, 256, 256, vdst, sv, dv);
  k_hist<<<N_EDGES/256, 256, 0, stream>>>(dstp, csr_cnt);
  k_scan<<<1, 1024, 0, stream>>>(csr_cnt, csr_off);
  k_scatter<<<N_EDGES/256, 256, 0, stream>>>(dstp, csr_off, csr_cnt, csr_eid);
  k_agg<<<N_NODES/4, 256, 0, stream>>>(csr_eid, csr_off, srcp, sv, dv, hs, b1, emb, 0, 1);

  // GAT layer 2 (input = h1 in emb cols 0..127)
  k_gemm128<<<N_NODES/16, 256, 0, stream>>>(emb, 256, 128, Wsrc2, hs);
  k_sd<<<N_NODES/4, 256, 0, stream>>>(hs, asrc2, emb, 256, 128, vdst+256, sv, dv);
  k_agg<<<N_NODES/4, 256, 0, stream>>>(csr_eid, csr_off, srcp, sv, dv, hs, b2, emb, 128, 0);

  // GRU input gates + scan
  k_xg<<<N_NODES/16, 256, 0, stream>>>(emb, Wi, bi, xg);
  const int GRU_LDS = (32*768 + 128)*4 + (768 + 2*768)*4;   // 108,032 B
  hipFuncSetAttribute((const void*)k_gru2, hipFuncAttributeMaxDynamicSharedMemorySize, GRU_LDS);
  k_gru2<<<BATCH, 768, GRU_LDS, stream>>>(xg, Wh, bh, hseq);

  // attention pooling + MLP head
  k_scores<<<N_NODES/4, 256, 0, stream>>>(hseq, w_att, b_att, scores);
  k_final<<<BATCH, 256, 0, stream>>>(scores, lengths, hseq, fc1_w, fc1_b, fc2_w, fc2_b, out);
}